// Round 8
// baseline (520.624 us; speedup 1.0000x reference)
//
#include <hip/hip_runtime.h>

// ---------------------------------------------------------------------------
// TransformerEncoder: B=4, S=2048, D=1024, H=16, HD=64, FF=4096
// Round 8: S^T-form flash attention using ONLY the verified 16x16x32 MFMA.
//   P^T C-frags are re-gathered into K=32 B-frags via 64-bit lane shuffles
//   (no LDS round-trip, no unverified K=16 instruction).
//   GEMMs: m-band XCD swizzle (A-slab pinned in per-XCD L2).
// ---------------------------------------------------------------------------

typedef short bf16x8 __attribute__((ext_vector_type(8)));
typedef float f32x4 __attribute__((ext_vector_type(4)));

__device__ __forceinline__ unsigned short f2bf(float f) {
  unsigned int u = __builtin_bit_cast(unsigned int, f);
  u += 0x7fffu + ((u >> 16) & 1u);   // round-to-nearest-even
  return (unsigned short)(u >> 16);
}

__device__ __forceinline__ void gload16(const unsigned short* g, unsigned short* l) {
  __builtin_amdgcn_global_load_lds(
      (const __attribute__((address_space(1))) unsigned int*)(g),
      (__attribute__((address_space(3))) unsigned int*)(l),
      16, 0, 0);
}

// --------------------------- cast fp32 -> bf16 -----------------------------
__global__ __launch_bounds__(256) void cast_f32_bf16(
    const float* __restrict__ src, unsigned short* __restrict__ dst, int n4) {
  int i = blockIdx.x * 256 + threadIdx.x;
  if (i < n4) {
    float4 f = ((const float4*)src)[i];
    ushort4 o;
    o.x = f2bf(f.x); o.y = f2bf(f.y); o.z = f2bf(f.z); o.w = f2bf(f.w);
    ((ushort4*)dst)[i] = o;
  }
}

// ---------------- merged weight prep: 6 transposes in one kernel -----------
__global__ __launch_bounds__(256) void prep_weights(
    const float* __restrict__ qW, const float* __restrict__ kW,
    const float* __restrict__ vW, const float* __restrict__ oW,
    const float* __restrict__ w1, const float* __restrict__ w2,
    unsigned short* __restrict__ qWt, unsigned short* __restrict__ kWt,
    unsigned short* __restrict__ vWt, unsigned short* __restrict__ oWt,
    unsigned short* __restrict__ w1t, unsigned short* __restrict__ w2t) {
  const int t = blockIdx.x;
  const float* W; unsigned short* Wt; int N, K, nt, kt;
  if (t < 2048) {
    const int w = t >> 9, r = t & 511;
    nt = r & 15; kt = r >> 4; N = 1024; K = 1024;
    W  = w == 0 ? qW : w == 1 ? kW : w == 2 ? vW : oW;
    Wt = w == 0 ? qWt : w == 1 ? kWt : w == 2 ? vWt : oWt;
  } else if (t < 4096) {
    const int r = t - 2048;
    nt = r & 63; kt = r >> 6; N = 4096; K = 1024; W = w1; Wt = w1t;
  } else {
    const int r = t - 4096;
    nt = r & 15; kt = r >> 4; N = 1024; K = 4096; W = w2; Wt = w2t;
  }
  const int wave = threadIdx.x >> 6, lane = threadIdx.x & 63;
  const int n = nt * 64 + lane;
  const int k0 = kt * 32 + wave * 8;
  union { int4 v; unsigned short u[8]; } s;
#pragma unroll
  for (int j = 0; j < 8; ++j) s.u[j] = f2bf(W[(size_t)(k0 + j) * N + n]);
  *(int4*)(Wt + (size_t)n * K + k0) = s.v;
}

// ------------------------------- GEMM (B^T) --------------------------------
// C[M,N] = A[M,K] @ Bt[N,K]^T + bias[N].  EPI: 0 fp32, 1 bf16, 2 bf16+relu.
// SWZ=1: m-band per XCD (A-slab pinned in per-XCD L2, B streams).
// SWZ=0: n-band per XCD (for FF2 where the K=4096 A-slab exceeds L2).
template <int EPI, int SWZ>
__global__ __launch_bounds__(256) void gemm_bt(
    const unsigned short* __restrict__ A, const unsigned short* __restrict__ Bt,
    const float* __restrict__ bias, void* __restrict__ C,
    int M, int N, int K) {
  __shared__ unsigned short As[128 * 32];
  __shared__ unsigned short Bs[128 * 32];

  const int tid = threadIdx.x;
  const int wave = tid >> 6, lane = tid & 63;
  const int quad = lane >> 4, l16 = lane & 15;
  const int wm = (wave >> 1) * 64, wn = (wave & 1) * 64;

  int mt, nt;
  const int xcd = blockIdx.x & 7, local = blockIdx.x >> 3;
  if (SWZ == 1) {
    const int mb = (M >> 7) >> 3;           // m-tiles per band (pow2)
    mt = xcd * mb + (local & (mb - 1));
    nt = local / mb;
  } else {
    const int band = (N >> 7) >> 3;
    nt = xcd * band + local % band;
    mt = local / band;
  }
  const int m0 = mt * 128, n0 = nt * 128;

  const int u1 = tid, u2 = 256 + tid;
  const int r1 = u1 >> 2, c1 = (u1 & 3) * 8;
  const int r2 = u2 >> 2, c2 = (u2 & 3) * 8;
  const unsigned short* ga1 = A + (size_t)(m0 + r1) * K + c1;
  const unsigned short* ga2 = A + (size_t)(m0 + r2) * K + c2;
  const unsigned short* gb1 = Bt + (size_t)(n0 + r1) * K + c1;
  const unsigned short* gb2 = Bt + (size_t)(n0 + r2) * K + c2;
  unsigned short* lA1 = As + wave * 512;
  unsigned short* lA2 = As + 2048 + wave * 512;
  unsigned short* lB1 = Bs + wave * 512;
  unsigned short* lB2 = Bs + 2048 + wave * 512;

  f32x4 acc[4][4] = {};

  for (int k0 = 0; k0 < K; k0 += 32) {
    __syncthreads();
    gload16(ga1 + k0, lA1);
    gload16(ga2 + k0, lA2);
    gload16(gb1 + k0, lB1);
    gload16(gb2 + k0, lB2);
    __syncthreads();

    bf16x8 af[4], bfr[4];
#pragma unroll
    for (int mi = 0; mi < 4; ++mi)
      af[mi] = *(const bf16x8*)(As + (wm + mi * 16 + l16) * 32 + quad * 8);
#pragma unroll
    for (int ni = 0; ni < 4; ++ni)
      bfr[ni] = *(const bf16x8*)(Bs + (wn + ni * 16 + l16) * 32 + quad * 8);
#pragma unroll
    for (int mi = 0; mi < 4; ++mi)
#pragma unroll
      for (int ni = 0; ni < 4; ++ni)
        acc[mi][ni] = __builtin_amdgcn_mfma_f32_16x16x32_bf16(
            af[mi], bfr[ni], acc[mi][ni], 0, 0, 0);
  }

#pragma unroll
  for (int ni = 0; ni < 4; ++ni) {
    const int col = n0 + wn + ni * 16 + l16;
    const float bv = bias[col];
#pragma unroll
    for (int mi = 0; mi < 4; ++mi) {
      const int row = m0 + wm + mi * 16 + quad * 4;
#pragma unroll
      for (int r = 0; r < 4; ++r) {
        float v = acc[mi][ni][r] + bv;
        if (EPI == 2) v = v > 0.f ? v : 0.f;
        if (EPI == 0)
          ((float*)C)[(size_t)(row + r) * N + col] = v;
        else
          ((unsigned short*)C)[(size_t)(row + r) * N + col] = f2bf(v);
      }
    }
  }
}

// --------------------------- fused QKV GEMM --------------------------------
#define QSCALE 0.180336884f   // 0.125 * log2(e)

__global__ __launch_bounds__(256) void gemm_qkv(
    const unsigned short* __restrict__ A, const unsigned short* __restrict__ Bt,
    const float* __restrict__ qb, const float* __restrict__ kb,
    const float* __restrict__ vb, unsigned short* __restrict__ Qo,
    unsigned short* __restrict__ Ko, unsigned short* __restrict__ Vto,
    int M, int K) {
  __shared__ unsigned short As[128 * 32];
  __shared__ unsigned short Bs[128 * 32];

  const int tid = threadIdx.x;
  const int wave = tid >> 6, lane = tid & 63;
  const int quad = lane >> 4, l16 = lane & 15;
  const int wm = (wave >> 1) * 64, wn = (wave & 1) * 64;

  // m-band per XCD: 8 m-tiles/XCD (A-slab 2 MiB), m-fastest within band
  const int xcd = blockIdx.x & 7, local = blockIdx.x >> 3;
  const int mt = xcd * 8 + (local & 7);
  const int nt = local >> 3;                 // 0..23
  const int m0 = mt * 128, n0 = nt * 128;

  const int u1 = tid, u2 = 256 + tid;
  const int r1 = u1 >> 2, c1 = (u1 & 3) * 8;
  const int r2 = u2 >> 2, c2 = (u2 & 3) * 8;
  const unsigned short* ga1 = A + (size_t)(m0 + r1) * K + c1;
  const unsigned short* ga2 = A + (size_t)(m0 + r2) * K + c2;
  const unsigned short* gb1 = Bt + (size_t)(n0 + r1) * K + c1;
  const unsigned short* gb2 = Bt + (size_t)(n0 + r2) * K + c2;
  unsigned short* lA1 = As + wave * 512;
  unsigned short* lA2 = As + 2048 + wave * 512;
  unsigned short* lB1 = Bs + wave * 512;
  unsigned short* lB2 = Bs + 2048 + wave * 512;

  f32x4 acc[4][4] = {};

  for (int k0 = 0; k0 < K; k0 += 32) {
    __syncthreads();
    gload16(ga1 + k0, lA1);
    gload16(ga2 + k0, lA2);
    gload16(gb1 + k0, lB1);
    gload16(gb2 + k0, lB2);
    __syncthreads();

    bf16x8 af[4], bfr[4];
#pragma unroll
    for (int mi = 0; mi < 4; ++mi)
      af[mi] = *(const bf16x8*)(As + (wm + mi * 16 + l16) * 32 + quad * 8);
#pragma unroll
    for (int ni = 0; ni < 4; ++ni)
      bfr[ni] = *(const bf16x8*)(Bs + (wn + ni * 16 + l16) * 32 + quad * 8);
#pragma unroll
    for (int mi = 0; mi < 4; ++mi)
#pragma unroll
      for (int ni = 0; ni < 4; ++ni)
        acc[mi][ni] = __builtin_amdgcn_mfma_f32_16x16x32_bf16(
            af[mi], bfr[ni], acc[mi][ni], 0, 0, 0);
  }

  const int seg = n0 >> 10;   // 0=Q, 1=K, 2=V (block-uniform)
  const float* bias = seg == 0 ? qb : (seg == 1 ? kb : vb);
#pragma unroll
  for (int ni = 0; ni < 4; ++ni) {
    const int col = (n0 + wn + ni * 16 + l16) & 1023;
    const float bv = bias[col];
#pragma unroll
    for (int mi = 0; mi < 4; ++mi) {
      const int row = m0 + wm + mi * 16 + quad * 4;
      if (seg == 2) {
        const int b = row >> 11, s = row & 2047;
        const int h = col >> 6, dh = col & 63;
        union { ushort4 v; unsigned short u[4]; } pk;
#pragma unroll
        for (int r = 0; r < 4; ++r) pk.u[r] = f2bf(acc[mi][ni][r] + bv);
        *(ushort4*)(Vto + ((size_t)((b * 16 + h) * 64 + dh)) * 2048 + s) = pk.v;
      } else {
#pragma unroll
        for (int r = 0; r < 4; ++r) {
          float v = acc[mi][ni][r] + bv;
          if (seg == 0)
            Qo[(size_t)(row + r) * 1024 + col] = f2bf(v * QSCALE);
          else
            Ko[(size_t)(row + r) * 1024 + col] = f2bf(v);
        }
      }
    }
  }
}

// --------------------------- flash attention (S^T form) --------------------
// Block = (b, h, 128-q tile); 512 thr = 8 waves, wave owns 16 q (MFMA n-dim).
// S^T = K @ Q^T via the verified 16x16x32 MFMA (C: col=q=l16, row=key=quad*4+r).
// After exp2, each lane packs its 4 p-values (keys quad*4+r of a 16-key block)
// into 64 bits; lane shuffles regroup them into the K=32 B-operand layout
// (k = quad*8+j): for target lane (quad,l16), element j of key-block kb2 comes
// from source lane ((quad&1)*2 + (j>>2))*16 + l16, element j&3, of C-frag
// cb = kb2*2 + (quad>>1) — element order preserved, so two 64-bit shuffles
// per source frag suffice. PV: O^T = Vt @ P^T, K=32 MFMA, no LDS round-trip.
// No max-tracking (logits bounded; Q pre-scaled by 0.125*log2e).
__global__ __launch_bounds__(512) void attn_fused(
    const unsigned short* __restrict__ Q, const unsigned short* __restrict__ K,
    const unsigned short* __restrict__ Vt, const int* __restrict__ lengths,
    unsigned short* __restrict__ ctx) {
  constexpr int S = 2048, D = 1024;
  __shared__ unsigned short Ks[64 * 72];   // [key][dh+pad]
  __shared__ unsigned short Vs[64 * 72];   // [dh][key+pad]

  const int tid = threadIdx.x;
  const int wave = tid >> 6, lane = tid & 63;
  const int quad = lane >> 4, l16 = lane & 15;
  const int bid = blockIdx.x;
  const int qt = bid & 15;
  const int h = (bid >> 4) & 15;
  const int b = bid >> 8;
  const int q0 = qt * 128;
  const int len = lengths[b];
  const int ktEnd = (len + 63) >> 6;
  const float NEGINF = -__builtin_inff();

  const size_t xbase = (size_t)b * S * D + (size_t)h * 64;
  const size_t vtb = (size_t)(b * 16 + h) * 64;

  // Q fragment as B-operand of K=32 MFMA: n = q (l16), k = dh (quad*8+j)
  const unsigned short* qrow = Q + xbase + (size_t)(q0 + wave * 16 + l16) * D;
  const bf16x8 qf0 = *(const bf16x8*)(qrow + quad * 8);
  const bf16x8 qf1 = *(const bf16x8*)(qrow + 32 + quad * 8);

  // staging (512 thr, 1 int4 each per buffer): row = tid>>3, col = (tid&7)*8
  const int sr = tid >> 3, sc = (tid & 7) * 8;
  const unsigned short* kg = K + xbase + (size_t)sr * D + sc;
  const unsigned short* vg = Vt + (vtb + sr) * S + sc;

  f32x4 oaccT[4] = {};   // O^T: row = dh (db*16+quad*4+r), col = q (l16)
  float rs = 0.f;        // partial row-sum for q=l16 (this quad's keys)

  const int src0 = ((quad & 1) * 2) * 16 + l16;   // shuffle source lanes
  const int src1 = src0 + 16;

  for (int kt = 0; kt < ktEnd; ++kt) {
    const int k0 = kt * 64;
    __syncthreads();
    *(int4*)(Ks + sr * 72 + sc) = *(const int4*)(kg + (size_t)k0 * D);
    *(int4*)(Vs + sr * 72 + sc) = *(const int4*)(vg + k0);
    __syncthreads();

    const bool bnd = (k0 + 64 > len);
    long long pp[4];
#pragma unroll
    for (int cb = 0; cb < 4; ++cb) {
      // S^T block: A = K-frag (m = key), B = Q-frag (n = q)
      const bf16x8 kf0 = *(const bf16x8*)(Ks + (cb * 16 + l16) * 72 + quad * 8);
      const bf16x8 kf1 = *(const bf16x8*)(Ks + (cb * 16 + l16) * 72 + 32 + quad * 8);
      f32x4 c = {0.f, 0.f, 0.f, 0.f};
      c = __builtin_amdgcn_mfma_f32_16x16x32_bf16(kf0, qf0, c, 0, 0, 0);
      c = __builtin_amdgcn_mfma_f32_16x16x32_bf16(kf1, qf1, c, 0, 0, 0);

      if (bnd) {
#pragma unroll
        for (int r = 0; r < 4; ++r)
          if (k0 + cb * 16 + quad * 4 + r >= len) c[r] = NEGINF;
      }

      // p = exp2(s); accumulate row-sum; pack 4 bf16 p-values into 64 bits
      union { long long ll; unsigned short u[4]; } pb;
#pragma unroll
      for (int r = 0; r < 4; ++r) {
        const float p = __builtin_amdgcn_exp2f(c[r]);
        rs += p;
        pb.u[r] = f2bf(p);
      }
      pp[cb] = pb.ll;
    }

    // regroup P^T into K=32 B-frags via lane shuffles, run PV
#pragma unroll
    for (int kb2 = 0; kb2 < 2; ++kb2) {
      const long long a0 = __shfl(pp[kb2 * 2], src0);
      const long long a1 = __shfl(pp[kb2 * 2], src1);
      const long long b0 = __shfl(pp[kb2 * 2 + 1], src0);
      const long long b1 = __shfl(pp[kb2 * 2 + 1], src1);
      union { bf16x8 v; long long ll[2]; } pB;
      pB.ll[0] = (quad < 2) ? a0 : b0;
      pB.ll[1] = (quad < 2) ? a1 : b1;
#pragma unroll
      for (int db = 0; db < 4; ++db) {
        const bf16x8 va =
            *(const bf16x8*)(Vs + (db * 16 + l16) * 72 + kb2 * 32 + quad * 8);
        oaccT[db] = __builtin_amdgcn_mfma_f32_16x16x32_bf16(
            va, pB.v, oaccT[db], 0, 0, 0);
      }
    }
  }

  // reduce row-sum across the 4 quads holding this q's keys
  rs += __shfl_xor(rs, 16);
  rs += __shfl_xor(rs, 32);
  const float inv = 1.0f / rs;

  // epilogue: O[q][dh] = O^T / l; 4 consecutive dh per lane -> 8B store
  unsigned short* crow = ctx + xbase + (size_t)(q0 + wave * 16 + l16) * D;
#pragma unroll
  for (int db = 0; db < 4; ++db) {
    union { ushort4 v; unsigned short u[4]; } pk;
#pragma unroll
    for (int r = 0; r < 4; ++r) pk.u[r] = f2bf(oaccT[db][r] * inv);
    *(ushort4*)(crow + db * 16 + quad * 4) = pk.v;
  }
}

// ------------------------------ launcher -----------------------------------
extern "C" void kernel_launch(void* const* d_in, const int* in_sizes, int n_in,
                              void* d_out, int out_size, void* d_ws,
                              size_t ws_size, hipStream_t stream) {
  const float* x  = (const float*)d_in[0];
  const int* lengths = (const int*)d_in[1];
  const float* qW = (const float*)d_in[2];
  const float* qb = (const float*)d_in[3];
  const float* kW = (const float*)d_in[4];
  const float* kb = (const float*)d_in[5];
  const float* vW = (const float*)d_in[6];
  const float* vb = (const float*)d_in[7];
  const float* oW = (const float*)d_in[8];
  const float* ob = (const float*)d_in[9];
  const float* w1 = (const float*)d_in[10];
  const float* b1 = (const float*)d_in[11];
  const float* w2 = (const float*)d_in[12];
  const float* b2 = (const float*)d_in[13];
  float* out = (float*)d_out;

  const int Bx = 4, S = 2048, D = 1024, FF = 4096;
  const int M = Bx * S;  // 8192

  unsigned short* p = (unsigned short*)d_ws;
  unsigned short* xb  = p; p += (size_t)M * D;
  unsigned short* qWt = p; p += (size_t)D * D;   // contiguous [3072,1024]
  unsigned short* kWt = p; p += (size_t)D * D;
  unsigned short* vWt = p; p += (size_t)D * D;
  unsigned short* oWt = p; p += (size_t)D * D;
  unsigned short* w1t = p; p += (size_t)D * FF;   // [FF, D]
  unsigned short* w2t = p; p += (size_t)FF * D;   // [D, FF]
  unsigned short* Qb  = p; p += (size_t)M * D;
  unsigned short* Kb  = p; p += (size_t)M * D;
  unsigned short* Vtb = p; p += (size_t)M * D;    // [B,H,64,S]
  unsigned short* Cb  = p; p += (size_t)M * D;
  unsigned short* Ab  = p; p += (size_t)M * D;
  unsigned short* Hb  = p; p += (size_t)M * FF;

  {
    int n4 = (int)((size_t)M * D / 4);
    cast_f32_bf16<<<dim3((n4 + 255) / 256), dim3(256), 0, stream>>>(x, xb, n4);
  }
  prep_weights<<<dim3(6144), dim3(256), 0, stream>>>(
      qW, kW, vW, oW, w1, w2, qWt, kWt, vWt, oWt, w1t, w2t);

  dim3 blk(256);
  gemm_qkv<<<dim3((3 * D / 128) * (M / 128)), blk, 0, stream>>>(
      xb, qWt, qb, kb, vb, Qb, Kb, Vtb, M, D);

  attn_fused<<<dim3(Bx * 16 * (S / 128)), dim3(512), 0, stream>>>(
      Qb, Kb, Vtb, lengths, Cb);

  gemm_bt<1, 1><<<dim3((D / 128) * (M / 128)), blk, 0, stream>>>(Cb, oWt, ob, Ab, M, D, D);
  gemm_bt<2, 1><<<dim3((FF / 128) * (M / 128)), blk, 0, stream>>>(Ab, w1t, b1, Hb, M, FF, D);
  gemm_bt<0, 0><<<dim3((D / 128) * (M / 128)), blk, 0, stream>>>(Hb, w2t, b2, out, M, D, FF);
}